// Round 1
// baseline (48.915 us; speedup 1.0000x reference)
//
#include <hip/hip_runtime.h>

#define BLOCK 256
#define GRID 2048

// Utility-function constants (compile-time evaluated, match reference f32 math)
// m_1 = 1/6, b_1 = 2; m_2 = -1/9, b_2 = 1/3; m_3 = -2/9, b_3 = -4/3
__device__ __forceinline__ float util_elem(float p, int flag, float s, float c) {
    // d = current - (sepsis - dt_optimal) = current - sepsis - 6.0
    float d = c - s - 6.0f;
    if (d > 3.0f) return 0.0f;            // outside window -> all utilities 0
    float u;
    if (flag) {
        float uTP, uFN;
        if (d <= -6.0f) {
            uTP = fmaxf(fmaf(d, 1.0f / 6.0f, 2.0f), -0.05f);
            uFN = 0.0f;
        } else {
            uTP = fmaf(d, -1.0f / 9.0f, 1.0f / 3.0f);
            uFN = fmaf(d, -2.0f / 9.0f, -4.0f / 3.0f);
        }
        u = p * uTP + (1.0f - p) * uFN;
    } else {
        u = p * -0.05f;                   // u_FP branch; u_TN == 0
    }
    return u;
}

__device__ __forceinline__ float block_reduce_sum(float v) {
    __shared__ float smem[BLOCK / 64];
    #pragma unroll
    for (int o = 32; o > 0; o >>= 1) v += __shfl_down(v, o, 64);
    int lane = threadIdx.x & 63;
    int wid  = threadIdx.x >> 6;
    if (lane == 0) smem[wid] = v;
    __syncthreads();
    if (wid == 0) {
        v = (lane < BLOCK / 64) ? smem[lane] : 0.0f;
        #pragma unroll
        for (int o = (BLOCK / 64) / 2; o > 0; o >>= 1) v += __shfl_down(v, o, 64);
    }
    return v;  // valid in thread 0
}

__global__ __launch_bounds__(BLOCK) void util_partial(
    const float4* __restrict__ pred, const int4* __restrict__ flg,
    const float4* __restrict__ ts,   const float4* __restrict__ tc,
    float* __restrict__ partials, int n4) {
    float acc = 0.0f;
    int stride = gridDim.x * blockDim.x;
    for (int i = blockIdx.x * blockDim.x + threadIdx.x; i < n4; i += stride) {
        float4 p = pred[i];
        int4   f = flg[i];
        float4 s = ts[i];
        float4 c = tc[i];
        acc += util_elem(p.x, f.x, s.x, c.x);
        acc += util_elem(p.y, f.y, s.y, c.y);
        acc += util_elem(p.z, f.z, s.z, c.z);
        acc += util_elem(p.w, f.w, s.w, c.w);
    }
    float bsum = block_reduce_sum(acc);
    if (threadIdx.x == 0) partials[blockIdx.x] = bsum;
}

__global__ __launch_bounds__(BLOCK) void util_final(
    const float* __restrict__ partials, float* __restrict__ out, int n) {
    float v = 0.0f;
    for (int i = threadIdx.x; i < n; i += BLOCK) v += partials[i];
    float total = block_reduce_sum(v);
    if (threadIdx.x == 0) out[0] = -total;   // loss = sum(-u)
}

extern "C" void kernel_launch(void* const* d_in, const int* in_sizes, int n_in,
                              void* d_out, int out_size, void* d_ws, size_t ws_size,
                              hipStream_t stream) {
    const float4* pred = (const float4*)d_in[0];
    // d_in[1] = targets: unused by the reference loss -> never read (saves 64 MB)
    const int4*   flg  = (const int4*)d_in[2];
    const float4* ts   = (const float4*)d_in[3];
    const float4* tc   = (const float4*)d_in[4];

    int n  = in_sizes[0];
    int n4 = n / 4;  // N = 16,777,216 divisible by 4

    float* partials = (float*)d_ws;
    float* out = (float*)d_out;

    util_partial<<<GRID, BLOCK, 0, stream>>>(pred, flg, ts, tc, partials, n4);
    util_final<<<1, BLOCK, 0, stream>>>(partials, out, GRID);
}